// Round 5
// baseline (119.701 us; speedup 1.0000x reference)
//
#include <hip/hip_runtime.h>
#include <cfloat>

#define NEG_INF_F (-1e30f)

constexpr int BB = 8, SS = 4096, HH = 1024;
constexpr int TOTAL = BB * SS;
constexpr int MAXLEN = 30;

// ---------------- Kernel 1: QA-head GEMV + masking ----------------
// One wave per (b,s) row; 134 MB of X at ~6.2 TB/s ≈ 20-21 us (measured R1-R3;
// 98% of achievable HBM BW -> this kernel is at its roofline).
__global__ __launch_bounds__(256) void qa_logits_kernel(
    const float* __restrict__ X,     // (B*S, H)
    const float* __restrict__ mask,  // (B*S)
    const float* __restrict__ W,     // (H, 2) row-major
    const float* __restrict__ bqa,   // (2)
    float* __restrict__ out) {       // [0,TOTAL): start, [TOTAL,2*TOTAL): end
  int row  = (int)((blockIdx.x * (size_t)blockDim.x + threadIdx.x) >> 6);
  int lane = threadIdx.x & 63;
  if (row >= TOTAL) return;
  const float* rp = X + (size_t)row * HH;
  float s0 = 0.f, s1 = 0.f;
#pragma unroll
  for (int k = 0; k < HH / 256; ++k) {
    int h = (k * 64 + lane) * 4;
    const float4 x   = *reinterpret_cast<const float4*>(rp + h);
    const float4 w01 = *reinterpret_cast<const float4*>(W + 2 * h);
    const float4 w23 = *reinterpret_cast<const float4*>(W + 2 * h + 4);
    s0 += x.x * w01.x + x.y * w01.z + x.z * w23.x + x.w * w23.z;
    s1 += x.x * w01.y + x.y * w01.w + x.z * w23.y + x.w * w23.w;
  }
#pragma unroll
  for (int off = 32; off > 0; off >>= 1) {
    s0 += __shfl_down(s0, off);
    s1 += __shfl_down(s1, off);
  }
  if (lane == 0) {
    float m = mask[row];
    float inv = 1.f - m;
    out[row]         = (s0 + bqa[0]) * m + inv * NEG_INF_F;
    out[TOTAL + row] = (s1 + bqa[1]) * m + inv * NEG_INF_F;
  }
}

// ---------------- Kernel 2: fused banded top-5 (one block per batch) -------
// Valid spans: i in [4,S), j in [i, i+30) ∩ [0,S), plus (1,1),(2,2),(3,3).

__device__ __forceinline__ bool t5_better(float av, int ai, float bv, int bi) {
  // jax top_k tie-break: lower flat index wins on equal value
  return av > bv || (av == bv && ai < bi);
}

// Sorted-descending 5-list insert; all indices compile-time (no scratch).
__device__ __forceinline__ void t5_insert(float v[5], int id[5], float nv, int ni) {
  if (!t5_better(nv, ni, v[4], id[4])) return;
  v[4] = nv; id[4] = ni;
#pragma unroll
  for (int q = 4; q > 0; --q) {
    if (t5_better(v[q], id[q], v[q - 1], id[q - 1])) {
      float tv = v[q]; v[q] = v[q - 1]; v[q - 1] = tv;
      int ti = id[q]; id[q] = id[q - 1]; id[q - 1] = ti;
    }
  }
}

__device__ __forceinline__ void t5_init(float v[5], int id[5]) {
#pragma unroll
  for (int q = 0; q < 5; ++q) { v[q] = -FLT_MAX; id[q] = 0x7fffffff; }
}

// Wave-wide top-5 of each lane's local sorted-5 list, via 5 argmax rounds.
__device__ __forceinline__ void wave_top5(float v[5], int id[5],
                                          float rv[5], int rid[5]) {
#pragma unroll
  for (int r = 0; r < 5; ++r) {
    float bv = v[0]; int bi = id[0];
#pragma unroll
    for (int q = 1; q < 5; ++q)
      if (t5_better(v[q], id[q], bv, bi)) { bv = v[q]; bi = id[q]; }
#pragma unroll
    for (int off = 1; off < 64; off <<= 1) {
      float ov = __shfl_xor(bv, off);
      int oi = __shfl_xor(bi, off);
      if (t5_better(ov, oi, bv, bi)) { bv = ov; bi = oi; }
    }
    rv[r] = bv; rid[r] = bi;
    // invalidate winner in its owning lane (candidate ids are unique)
#pragma unroll
    for (int q = 0; q < 5; ++q)
      if (id[q] == bi) v[q] = -FLT_MAX;
  }
}

#define T2 1024  // 16 waves per block; 4 rows per thread

__global__ __launch_bounds__(T2) void topk_fused(
    const float* __restrict__ logits,  // kernel-1 output (start then end)
    float* __restrict__ out) {
  const int b = blockIdx.x;
  const float* st = logits + (size_t)b * SS;
  const float* en = logits + (size_t)(BB + b) * SS;
  const int t = (int)threadIdx.x;
  const int lane = t & 63;
  const int w = t >> 6;

  float v[5]; int id[5];
  t5_init(v, id);

#pragma unroll
  for (int rr = 0; rr < SS / T2; ++rr) {
    int i = rr * T2 + t;
    if (i >= 4) {
      float si = st[i];
      float e[MAXLEN];
#pragma unroll
      for (int c = 0; c < MAXLEN; ++c) {
        int j = i + c;
        e[c] = (j < SS) ? en[j] : NEG_INF_F;  // loads issued before inserts
      }
      int base = i * SS + i;
#pragma unroll
      for (int c = 0; c < MAXLEN; ++c) t5_insert(v, id, si + e[c], base + c);
    } else if (i >= 1) {
      t5_insert(v, id, st[i] + en[i], i * SS + i);  // (1,1),(2,2),(3,3)
    }
  }

  float rv[5]; int rid[5];
  wave_top5(v, id, rv, rid);

  __shared__ float sv[(T2 / 64) * 5];
  __shared__ int   sid[(T2 / 64) * 5];
  if (lane == 0) {
#pragma unroll
    for (int q = 0; q < 5; ++q) { sv[w * 5 + q] = rv[q]; sid[w * 5 + q] = rid[q]; }
  }
  __syncthreads();

  if (w == 0) {  // wave 0 merges 16 waves * 5 = 80 candidates
    float fv[5]; int fid[5];
    t5_init(fv, fid);
    for (int c = lane; c < (T2 / 64) * 5; c += 64)
      t5_insert(fv, fid, sv[c], sid[c]);
    float gv[5]; int gid[5];
    wave_top5(fv, fid, gv, gid);
    if (lane == 0) {
      float* ts = out + 2 * (size_t)TOTAL;  // top_start region
      float* te = ts + BB * 5;              // top_end region
#pragma unroll
      for (int q = 0; q < 5; ++q) {
        ts[b * 5 + q] = (float)(gid[q] >> 12);       // id / S  (S=4096)
        te[b * 5 + q] = (float)(gid[q] & (SS - 1));  // id % S
      }
    }
  }
}

extern "C" void kernel_launch(void* const* d_in, const int* in_sizes, int n_in,
                              void* d_out, int out_size, void* d_ws, size_t ws_size,
                              hipStream_t stream) {
  const float* X    = (const float*)d_in[0];  // (B,S,H)
  const float* mask = (const float*)d_in[1];  // (B,S)
  const float* W    = (const float*)d_in[2];  // (H,2)
  const float* bqa  = (const float*)d_in[3];  // (2)
  float* out = (float*)d_out;

  // Kernel 1: one wave per row, 4 waves per 256-thread block.
  int blocks = TOTAL / 4;
  qa_logits_kernel<<<blocks, 256, 0, stream>>>(X, mask, W, bqa, out);

  // Kernel 2: one 1024-thread block per batch.
  topk_fused<<<BB, T2, 0, stream>>>(out, out);
}